// Round 1
// baseline (250.559 us; speedup 1.0000x reference)
//
#include <hip/hip_runtime.h>

// Shapes: genes[32][2048][4], smiles[32][2048][1024], w_ngf[4], w_genes[2048][512],
//         b_genes[512], w_smiles[1024][512], b_smiles[512], v[512] -> out[32][1024]

typedef __bf16 bf16_t;
typedef bf16_t bf16x8 __attribute__((ext_vector_type(8)));
typedef float f32x4 __attribute__((ext_vector_type(4)));

__device__ __forceinline__ unsigned short f32_to_bf16_rne(float f) {
    unsigned int u = __builtin_bit_cast(unsigned int, f);
    u = (u + 0x7FFFu + ((u >> 16) & 1u)) >> 16;
    return (unsigned short)u;
}

__device__ __forceinline__ float fast_tanh(float x) {
    float cx = fminf(fmaxf(x, -30.f), 30.f);
    float e = __expf(2.f * cx);
    return (e - 1.f) / (e + 1.f);
}

// K0: w_smiles [1024][512] f32 -> bT [512][1024] bf16 (transposed, for contiguous-K B frags)
__global__ void k0_transpose(const float* __restrict__ w, unsigned short* __restrict__ bT) {
    __shared__ unsigned short tile[64][65];
    int h0 = blockIdx.x * 64, a0 = blockIdx.y * 64;
#pragma unroll
    for (int i = 0; i < 16; ++i) {
        int idx = i * 256 + threadIdx.x;
        int hr = idx >> 6, ac = idx & 63;
        tile[hr][ac] = f32_to_bf16_rne(w[(size_t)(h0 + hr) * 512 + (a0 + ac)]);
    }
    __syncthreads();
#pragma unroll
    for (int i = 0; i < 16; ++i) {
        int idx = i * 256 + threadIdx.x;
        int ar = idx >> 6, hc = idx & 63;
        bT[(size_t)(a0 + ar) * 1024 + (h0 + hc)] = tile[hc][ar];
    }
}

// K1a: gc[b][g] = dot(genes[b][g][0..3], w_ngf)
__global__ void k1a_gc(const float4* __restrict__ genes, const float* __restrict__ wngf,
                       float* __restrict__ gc) {
    int i = blockIdx.x * 256 + threadIdx.x;   // 65536 = 32*2048
    float4 g = genes[i];
    gc[i] = g.x * wngf[0] + g.y * wngf[1] + g.z * wngf[2] + g.w * wngf[3];
}

// K1b: x[b][a] += sum_{g in chunk} gc[b][g] * w_genes[g][a]   (x pre-zeroed)
__global__ void k1b_x(const float* __restrict__ gc, const float* __restrict__ wg,
                      float* __restrict__ x) {
    __shared__ float gcl[256];
    int bx = blockIdx.x;              // 512 = 32 b * 2 a-halves * 8 g-chunks
    int b = bx >> 4, ah = (bx >> 3) & 1, gch = bx & 7;
    int g0 = gch * 256;
    gcl[threadIdx.x] = gc[b * 2048 + g0 + threadIdx.x];
    __syncthreads();
    int a = ah * 256 + threadIdx.x;
    float s = 0.f;
#pragma unroll 8
    for (int g = 0; g < 256; ++g) s += gcl[g] * wg[(size_t)(g0 + g) * 512 + a];
    atomicAdd(&x[b * 512 + a], s);
}

// K2: the fused GEMM + tanh + dot(v) -> scores.
// Block: 64 rows (one batch each), full N=512, K=1024 in two LDS-staged halves.
// A-fragment layout assumption (16x16x32): row = lane&15, k = (lane>>4)*8 + e.
// C/D layout (HW-verified m89): col = lane&15, row = (lane>>4)*4 + reg.
__global__ __launch_bounds__(512, 2) void k2_scores(
    const float* __restrict__ smiles,
    const unsigned short* __restrict__ bT,
    const float* __restrict__ xraw,
    const float* __restrict__ b_genes,
    const float* __restrict__ b_smiles,
    const float* __restrict__ v,
    float* __restrict__ scores)
{
    __shared__ unsigned short A_lds[64 * 512];   // 64 KB, XOR-swizzled rows of 1024B
    const int tid  = threadIdx.x;
    const int wave = tid >> 6;
    const int lane = tid & 63;
    const int l15  = lane & 15;
    const int l4   = lane >> 4;
    const int gm0  = blockIdx.x * 64;            // 1024 blocks
    const int bidx = gm0 >> 11;                  // 2048 tokens per batch
    const int wbase = wave * 64;                 // wave's N-range [wbase, wbase+64)

    const f32x4 zero4 = {0.f, 0.f, 0.f, 0.f};
    f32x4 acc[4][4];
#pragma unroll
    for (int mt = 0; mt < 4; ++mt)
#pragma unroll
        for (int nt = 0; nt < 4; ++nt)
            acc[mt][nt] = zero4;

    for (int kh = 0; kh < 2; ++kh) {
        __syncthreads();   // protect previous half's LDS reads
        // stage A: 64 rows x 512 k (bf16), converted in-register from f32
#pragma unroll
        for (int it = 0; it < 8; ++it) {
            int chunk = it * 512 + tid;          // 4096 16B-chunks
            int row = chunk >> 6;
            int kc  = chunk & 63;
            const float* src = smiles + (size_t)(gm0 + row) * 1024 + kh * 512 + kc * 8;
            float4 f0 = *(const float4*)(src);
            float4 f1 = *(const float4*)(src + 4);
            union { unsigned short us[8]; uint4 u4; } pk;
            pk.us[0] = f32_to_bf16_rne(f0.x);
            pk.us[1] = f32_to_bf16_rne(f0.y);
            pk.us[2] = f32_to_bf16_rne(f0.z);
            pk.us[3] = f32_to_bf16_rne(f0.w);
            pk.us[4] = f32_to_bf16_rne(f1.x);
            pk.us[5] = f32_to_bf16_rne(f1.y);
            pk.us[6] = f32_to_bf16_rne(f1.z);
            pk.us[7] = f32_to_bf16_rne(f1.w);
            int byteoff = row * 1024 + ((kc * 16) ^ ((row & 7) << 4));
            *(uint4*)((char*)A_lds + byteoff) = pk.u4;
        }
        __syncthreads();

#pragma unroll 2
        for (int ks = 0; ks < 16; ++ks) {
            bf16x8 af[4], bfb[4];
#pragma unroll
            for (int mt = 0; mt < 4; ++mt) {
                int row = mt * 16 + l15;
                int kl  = ks * 32 + l4 * 8;
                int byteoff = row * 1024 + ((kl * 2) ^ ((row & 7) << 4));
                af[mt] = *(const bf16x8*)((const char*)A_lds + byteoff);
            }
            int kg = kh * 512 + ks * 32 + l4 * 8;
#pragma unroll
            for (int nt = 0; nt < 4; ++nt) {
                int a = wbase + nt * 16 + l15;
                bfb[nt] = *(const bf16x8*)(bT + (size_t)a * 1024 + kg);
            }
#pragma unroll
            for (int mt = 0; mt < 4; ++mt)
#pragma unroll
                for (int nt = 0; nt < 4; ++nt)
                    acc[mt][nt] = __builtin_amdgcn_mfma_f32_16x16x32_bf16(
                        af[mt], bfb[nt], acc[mt][nt], 0, 0, 0);
        }
    }

    // epilogue: score[row] += sum_a tanh(y + x + b_g + b_s) * v[a]  over this wave's 64 cols
    float xbv[4], vv[4];
#pragma unroll
    for (int nt = 0; nt < 4; ++nt) {
        int a = wbase + nt * 16 + l15;
        xbv[nt] = xraw[bidx * 512 + a] + b_genes[a] + b_smiles[a];
        vv[nt]  = v[a];
    }
    float rs[4][4];
#pragma unroll
    for (int mt = 0; mt < 4; ++mt)
#pragma unroll
        for (int r = 0; r < 4; ++r)
            rs[mt][r] = 0.f;
#pragma unroll
    for (int mt = 0; mt < 4; ++mt)
#pragma unroll
        for (int nt = 0; nt < 4; ++nt)
#pragma unroll
            for (int r = 0; r < 4; ++r)
                rs[mt][r] += vv[nt] * fast_tanh(acc[mt][nt][r] + xbv[nt]);
#pragma unroll
    for (int mt = 0; mt < 4; ++mt)
#pragma unroll
        for (int r = 0; r < 4; ++r) {
            float s = rs[mt][r];
            s += __shfl_xor(s, 1);
            s += __shfl_xor(s, 2);
            s += __shfl_xor(s, 4);
            s += __shfl_xor(s, 8);
            rs[mt][r] = s;
        }
    if (l15 == 0) {
#pragma unroll
        for (int mt = 0; mt < 4; ++mt)
#pragma unroll
            for (int r = 0; r < 4; ++r)
                atomicAdd(&scores[gm0 + mt * 16 + l4 * 4 + r], rs[mt][r]);
    }
}

// K3: softmax over t per batch
__global__ void k3_softmax(const float* __restrict__ scores, float* __restrict__ alphas) {
    __shared__ float redmax[4], redsum[4];
    int b = blockIdx.x, tid = threadIdx.x;   // 256 threads
    int wave = tid >> 6;
    float sv[8];
    float mx = -1e30f;
#pragma unroll
    for (int i = 0; i < 8; ++i) {
        sv[i] = scores[b * 2048 + i * 256 + tid];
        mx = fmaxf(mx, sv[i]);
    }
#pragma unroll
    for (int m = 32; m >= 1; m >>= 1) mx = fmaxf(mx, __shfl_xor(mx, m));
    if ((tid & 63) == 0) redmax[wave] = mx;
    __syncthreads();
    mx = fmaxf(fmaxf(redmax[0], redmax[1]), fmaxf(redmax[2], redmax[3]));
    float sum = 0.f;
#pragma unroll
    for (int i = 0; i < 8; ++i) {
        sv[i] = __expf(sv[i] - mx);
        sum += sv[i];
    }
#pragma unroll
    for (int m = 32; m >= 1; m >>= 1) sum += __shfl_xor(sum, m);
    if ((tid & 63) == 0) redsum[wave] = sum;
    __syncthreads();
    sum = redsum[0] + redsum[1] + redsum[2] + redsum[3];
    float inv = 1.f / sum;
#pragma unroll
    for (int i = 0; i < 8; ++i) alphas[b * 2048 + i * 256 + tid] = sv[i] * inv;
}

// K4: out[b][h] = sum_t alphas[b][t] * smiles[b][t][h]  (t-split x16, atomic f32)
__global__ void k4_out(const float* __restrict__ smiles,
                       const float* __restrict__ alphas,
                       float* __restrict__ out)
{
    int bx = blockIdx.x;              // 512 = 32 b * 16 t-chunks
    int b  = bx >> 4;
    int tc = bx & 15;
    int h  = threadIdx.x * 4;         // 256 threads -> 1024 h
    const float* sb = smiles + ((size_t)b * 2048 + tc * 128) * 1024;
    const float* al = alphas + b * 2048 + tc * 128;
    float4 acc = {0.f, 0.f, 0.f, 0.f};
#pragma unroll 4
    for (int t = 0; t < 128; ++t) {
        float a = al[t];
        float4 sv = *(const float4*)(sb + (size_t)t * 1024 + h);
        acc.x += a * sv.x;
        acc.y += a * sv.y;
        acc.z += a * sv.z;
        acc.w += a * sv.w;
    }
    float* o = out + b * 1024 + h;
    atomicAdd(o + 0, acc.x);
    atomicAdd(o + 1, acc.y);
    atomicAdd(o + 2, acc.z);
    atomicAdd(o + 3, acc.w);
}

extern "C" void kernel_launch(void* const* d_in, const int* in_sizes, int n_in,
                              void* d_out, int out_size, void* d_ws, size_t ws_size,
                              hipStream_t stream) {
    const float* genes    = (const float*)d_in[0];
    const float* smiles   = (const float*)d_in[1];
    const float* w_ngf    = (const float*)d_in[2];
    const float* w_genes  = (const float*)d_in[3];
    const float* b_genes  = (const float*)d_in[4];
    const float* w_smiles = (const float*)d_in[5];
    const float* b_smiles = (const float*)d_in[6];
    const float* v        = (const float*)d_in[7];
    float* out = (float*)d_out;

    char* ws = (char*)d_ws;
    unsigned short* bT = (unsigned short*)(ws);                        // 1 MB
    float* gc     = (float*)(ws + (1 << 20));                          // 256 KB
    float* x      = (float*)(ws + (1 << 20) + (256 << 10));            // 64 KB
    float* scores = (float*)(ws + (1 << 20) + (320 << 10));            // 256 KB
    float* alphas = (float*)(ws + (1 << 20) + (576 << 10));            // 256 KB

    // zero atomic-accumulation targets: out, and x+scores (contiguous)
    hipMemsetAsync(out, 0, (size_t)32 * 1024 * sizeof(float), stream);
    hipMemsetAsync(x, 0, (size_t)(64 + 256) * 1024, stream);

    k0_transpose<<<dim3(16, 8), 256, 0, stream>>>(w_smiles, bT);
    k1a_gc<<<256, 256, 0, stream>>>((const float4*)genes, w_ngf, gc);
    k1b_x<<<512, 256, 0, stream>>>(gc, w_genes, x);
    k2_scores<<<1024, 512, 0, stream>>>(smiles, bT, x, b_genes, b_smiles, v, scores);
    k3_softmax<<<32, 256, 0, stream>>>(scores, alphas);
    k4_out<<<512, 256, 0, stream>>>(smiles, alphas, out);
}

// Round 2
// 196.746 us; speedup vs baseline: 1.2735x; 1.2735x over previous
//
#include <hip/hip_runtime.h>

// Shapes: genes[32][2048][4], smiles[32][2048][1024], w_ngf[4], w_genes[2048][512],
//         b_genes[512], w_smiles[1024][512], b_smiles[512], v[512] -> out[32][1024]

typedef __bf16 bf16_t;
typedef bf16_t bf16x8 __attribute__((ext_vector_type(8)));
typedef float f32x4 __attribute__((ext_vector_type(4)));

__device__ __forceinline__ unsigned short f32_to_bf16_rne(float f) {
    unsigned int u = __builtin_bit_cast(unsigned int, f);
    u = (u + 0x7FFFu + ((u >> 16) & 1u)) >> 16;
    return (unsigned short)u;
}

__device__ __forceinline__ float fast_tanh(float x) {
    float cx = fminf(fmaxf(x, -30.f), 30.f);
    float e = __expf(2.f * cx);
    return (e - 1.f) / (e + 1.f);
}

// K0b: pack w_smiles [1024][512] f32 into FRAGMENT-MAJOR bf16 so k2's B loads are
// contiguous 1KB bursts instead of 16-line scatters.
// Bp[frag=atile*32+gks][lane][e] = w[gks*32 + (lane>>4)*8 + e][atile*16 + (lane&15)]
__global__ void k0b_pack(const float* __restrict__ w, unsigned short* __restrict__ Bp) {
    int bid  = blockIdx.x;        // 1024 = 32 atiles * 32 gks
    int lane = threadIdx.x;       // 64
    int atile = bid >> 5, gks = bid & 31;
    int col = atile * 16 + (lane & 15);
    int k0  = gks * 32 + (lane >> 4) * 8;
    unsigned short us[8];
#pragma unroll
    for (int e = 0; e < 8; ++e)
        us[e] = f32_to_bf16_rne(w[(size_t)(k0 + e) * 512 + col]);
    *(uint4*)(Bp + (size_t)bid * 512 + lane * 8) = *(const uint4*)us;
}

// K1a: gc[b][g] = dot(genes[b][g][0..3], w_ngf)
__global__ void k1a_gc(const float4* __restrict__ genes, const float* __restrict__ wngf,
                       float* __restrict__ gc) {
    int i = blockIdx.x * 256 + threadIdx.x;   // 65536 = 32*2048
    float4 g = genes[i];
    gc[i] = g.x * wngf[0] + g.y * wngf[1] + g.z * wngf[2] + g.w * wngf[3];
}

// K1b: x[b][a] += sum_{g in chunk} gc[b][g] * w_genes[g][a]   (x pre-zeroed)
__global__ void k1b_x(const float* __restrict__ gc, const float* __restrict__ wg,
                      float* __restrict__ x) {
    __shared__ float gcl[256];
    int bx = blockIdx.x;              // 512 = 32 b * 2 a-halves * 8 g-chunks
    int b = bx >> 4, ah = (bx >> 3) & 1, gch = bx & 7;
    int g0 = gch * 256;
    gcl[threadIdx.x] = gc[b * 2048 + g0 + threadIdx.x];
    __syncthreads();
    int a = ah * 256 + threadIdx.x;
    float s = 0.f;
#pragma unroll 8
    for (int g = 0; g < 256; ++g) s += gcl[g] * wg[(size_t)(g0 + g) * 512 + a];
    atomicAdd(&x[b * 512 + a], s);
}

// K2: fused GEMM + tanh + dot(v) -> scores.
// Block: 64 rows, full N=512 (8 waves x 64 cols), K=1024 in two LDS halves.
// B from fragment-packed Bp (contiguous 1KB per fragment, sequential per wave).
// launch_bounds(512,4): arch-VGPR capped ~64 so combined (incl. 64 acc AGPRs)
// fits 4 waves/SIMD -> 2 blocks/CU.
__global__ __launch_bounds__(512, 4) void k2_scores(
    const float* __restrict__ smiles,
    const unsigned short* __restrict__ Bp,
    const float* __restrict__ xraw,
    const float* __restrict__ b_genes,
    const float* __restrict__ b_smiles,
    const float* __restrict__ v,
    float* __restrict__ scores)
{
    __shared__ unsigned short A_lds[64 * 512];   // 64 KB, XOR-swizzled rows of 1024B
    const int tid  = threadIdx.x;
    const int wave = tid >> 6;
    const int lane = tid & 63;
    const int l15  = lane & 15;
    const int l4   = lane >> 4;
    const int gm0  = blockIdx.x * 64;            // 1024 blocks
    const int bidx = gm0 >> 11;
    const int wbase = wave * 64;

    // wave's packed-B base: fragments (wave*4+nt)*32 + gks, each 1KB (512 ushorts)
    const unsigned short* bpp = Bp + (size_t)(wave * 128) * 512 + lane * 8;

    const f32x4 zero4 = {0.f, 0.f, 0.f, 0.f};
    f32x4 acc[4][4];
#pragma unroll
    for (int mt = 0; mt < 4; ++mt)
#pragma unroll
        for (int nt = 0; nt < 4; ++nt)
            acc[mt][nt] = zero4;

    for (int kh = 0; kh < 2; ++kh) {
        __syncthreads();   // protect previous half's LDS reads
        // stage A: 64 rows x 512 k (bf16). 4 batches of 2x16B units/thread keeps
        // the staging register watermark at ~16 VGPRs.
        for (int half = 0; half < 4; ++half) {
            int u   = half * 1024 + tid * 2;     // 2 consecutive 16B units
            int row = u >> 6;
            int kc  = u & 63;                    // even
            const float* src = smiles + (size_t)(gm0 + row) * 1024 + kh * 512 + kc * 8;
            float4 f0 = *(const float4*)(src);
            float4 f1 = *(const float4*)(src + 4);
            float4 f2 = *(const float4*)(src + 8);
            float4 f3 = *(const float4*)(src + 12);
            union { unsigned short us[8]; uint4 u4; } p0, p1;
            p0.us[0] = f32_to_bf16_rne(f0.x); p0.us[1] = f32_to_bf16_rne(f0.y);
            p0.us[2] = f32_to_bf16_rne(f0.z); p0.us[3] = f32_to_bf16_rne(f0.w);
            p0.us[4] = f32_to_bf16_rne(f1.x); p0.us[5] = f32_to_bf16_rne(f1.y);
            p0.us[6] = f32_to_bf16_rne(f1.z); p0.us[7] = f32_to_bf16_rne(f1.w);
            p1.us[0] = f32_to_bf16_rne(f2.x); p1.us[1] = f32_to_bf16_rne(f2.y);
            p1.us[2] = f32_to_bf16_rne(f2.z); p1.us[3] = f32_to_bf16_rne(f2.w);
            p1.us[4] = f32_to_bf16_rne(f3.x); p1.us[5] = f32_to_bf16_rne(f3.y);
            p1.us[6] = f32_to_bf16_rne(f3.z); p1.us[7] = f32_to_bf16_rne(f3.w);
            int swz = (row & 7) << 4;
            *(uint4*)((char*)A_lds + row * 1024 + ((kc * 16) ^ swz))        = p0.u4;
            *(uint4*)((char*)A_lds + row * 1024 + (((kc + 1) * 16) ^ swz))  = p1.u4;
        }
        __syncthreads();

#pragma unroll 4
        for (int ks = 0; ks < 16; ++ks) {
            int gks = kh * 16 + ks;
            bf16x8 af[4], bfb[4];
#pragma unroll
            for (int nt = 0; nt < 4; ++nt)
                bfb[nt] = *(const bf16x8*)(bpp + (nt * 32 + gks) * 512);
#pragma unroll
            for (int mt = 0; mt < 4; ++mt) {
                int row = mt * 16 + l15;
                int kl  = ks * 32 + l4 * 8;
                int byteoff = row * 1024 + ((kl * 2) ^ ((row & 7) << 4));
                af[mt] = *(const bf16x8*)((const char*)A_lds + byteoff);
            }
#pragma unroll
            for (int mt = 0; mt < 4; ++mt)
#pragma unroll
                for (int nt = 0; nt < 4; ++nt)
                    acc[mt][nt] = __builtin_amdgcn_mfma_f32_16x16x32_bf16(
                        af[mt], bfb[nt], acc[mt][nt], 0, 0, 0);
        }
    }

    // epilogue: score[row] += sum_a tanh(y + x + b_g + b_s) * v[a]
    float xbv[4], vv[4];
#pragma unroll
    for (int nt = 0; nt < 4; ++nt) {
        int a = wbase + nt * 16 + l15;
        xbv[nt] = xraw[bidx * 512 + a] + b_genes[a] + b_smiles[a];
        vv[nt]  = v[a];
    }
    float rs[4][4];
#pragma unroll
    for (int mt = 0; mt < 4; ++mt)
#pragma unroll
        for (int r = 0; r < 4; ++r)
            rs[mt][r] = 0.f;
#pragma unroll
    for (int mt = 0; mt < 4; ++mt)
#pragma unroll
        for (int nt = 0; nt < 4; ++nt)
#pragma unroll
            for (int r = 0; r < 4; ++r)
                rs[mt][r] += vv[nt] * fast_tanh(acc[mt][nt][r] + xbv[nt]);
#pragma unroll
    for (int mt = 0; mt < 4; ++mt)
#pragma unroll
        for (int r = 0; r < 4; ++r) {
            float s = rs[mt][r];
            s += __shfl_xor(s, 1);
            s += __shfl_xor(s, 2);
            s += __shfl_xor(s, 4);
            s += __shfl_xor(s, 8);
            rs[mt][r] = s;
        }
    if (l15 == 0) {
#pragma unroll
        for (int mt = 0; mt < 4; ++mt)
#pragma unroll
            for (int r = 0; r < 4; ++r)
                atomicAdd(&scores[gm0 + mt * 16 + l4 * 4 + r], rs[mt][r]);
    }
}

// K3: softmax over t per batch
__global__ void k3_softmax(const float* __restrict__ scores, float* __restrict__ alphas) {
    __shared__ float redmax[4], redsum[4];
    int b = blockIdx.x, tid = threadIdx.x;   // 256 threads
    int wave = tid >> 6;
    float sv[8];
    float mx = -1e30f;
#pragma unroll
    for (int i = 0; i < 8; ++i) {
        sv[i] = scores[b * 2048 + i * 256 + tid];
        mx = fmaxf(mx, sv[i]);
    }
#pragma unroll
    for (int m = 32; m >= 1; m >>= 1) mx = fmaxf(mx, __shfl_xor(mx, m));
    if ((tid & 63) == 0) redmax[wave] = mx;
    __syncthreads();
    mx = fmaxf(fmaxf(redmax[0], redmax[1]), fmaxf(redmax[2], redmax[3]));
    float sum = 0.f;
#pragma unroll
    for (int i = 0; i < 8; ++i) {
        sv[i] = __expf(sv[i] - mx);
        sum += sv[i];
    }
#pragma unroll
    for (int m = 32; m >= 1; m >>= 1) sum += __shfl_xor(sum, m);
    if ((tid & 63) == 0) redsum[wave] = sum;
    __syncthreads();
    sum = redsum[0] + redsum[1] + redsum[2] + redsum[3];
    float inv = 1.f / sum;
#pragma unroll
    for (int i = 0; i < 8; ++i) alphas[b * 2048 + i * 256 + tid] = sv[i] * inv;
}

// K4: out[b][h] = sum_t alphas[b][t] * smiles[b][t][h]  (t-split x16, atomic f32)
__global__ void k4_out(const float* __restrict__ smiles,
                       const float* __restrict__ alphas,
                       float* __restrict__ out)
{
    int bx = blockIdx.x;              // 512 = 32 b * 16 t-chunks
    int b  = bx >> 4;
    int tc = bx & 15;
    int h  = threadIdx.x * 4;         // 256 threads -> 1024 h
    const float* sb = smiles + ((size_t)b * 2048 + tc * 128) * 1024;
    const float* al = alphas + b * 2048 + tc * 128;
    float4 acc = {0.f, 0.f, 0.f, 0.f};
#pragma unroll 4
    for (int t = 0; t < 128; ++t) {
        float a = al[t];
        float4 sv = *(const float4*)(sb + (size_t)t * 1024 + h);
        acc.x += a * sv.x;
        acc.y += a * sv.y;
        acc.z += a * sv.z;
        acc.w += a * sv.w;
    }
    float* o = out + b * 1024 + h;
    atomicAdd(o + 0, acc.x);
    atomicAdd(o + 1, acc.y);
    atomicAdd(o + 2, acc.z);
    atomicAdd(o + 3, acc.w);
}

extern "C" void kernel_launch(void* const* d_in, const int* in_sizes, int n_in,
                              void* d_out, int out_size, void* d_ws, size_t ws_size,
                              hipStream_t stream) {
    const float* genes    = (const float*)d_in[0];
    const float* smiles   = (const float*)d_in[1];
    const float* w_ngf    = (const float*)d_in[2];
    const float* w_genes  = (const float*)d_in[3];
    const float* b_genes  = (const float*)d_in[4];
    const float* w_smiles = (const float*)d_in[5];
    const float* b_smiles = (const float*)d_in[6];
    const float* v        = (const float*)d_in[7];
    float* out = (float*)d_out;

    char* ws = (char*)d_ws;
    unsigned short* Bp = (unsigned short*)(ws);                        // 1 MB packed B
    float* gc     = (float*)(ws + (1 << 20));                          // 256 KB
    float* x      = (float*)(ws + (1 << 20) + (256 << 10));            // 64 KB
    float* scores = (float*)(ws + (1 << 20) + (320 << 10));            // 256 KB
    float* alphas = (float*)(ws + (1 << 20) + (576 << 10));            // 256 KB

    hipMemsetAsync(out, 0, (size_t)32 * 1024 * sizeof(float), stream);
    hipMemsetAsync(x, 0, (size_t)(64 + 256) * 1024, stream);

    k0b_pack<<<1024, 64, 0, stream>>>(w_smiles, Bp);
    k1a_gc<<<256, 256, 0, stream>>>((const float4*)genes, w_ngf, gc);
    k1b_x<<<512, 256, 0, stream>>>(gc, w_genes, x);
    k2_scores<<<1024, 512, 0, stream>>>(smiles, Bp, x, b_genes, b_smiles, v, scores);
    k3_softmax<<<32, 256, 0, stream>>>(scores, alphas);
    k4_out<<<512, 256, 0, stream>>>(smiles, alphas, out);
}

// Round 3
// 162.458 us; speedup vs baseline: 1.5423x; 1.2111x over previous
//
#include <hip/hip_runtime.h>

// Shapes: genes[32][2048][4], smiles[32][2048][1024], w_ngf[4], w_genes[2048][512],
//         b_genes[512], w_smiles[1024][512], b_smiles[512], v[512] -> out[32][1024]

typedef __bf16 bf16_t;
typedef bf16_t bf16x8 __attribute__((ext_vector_type(8)));
typedef float f32x4 __attribute__((ext_vector_type(4)));

__device__ __forceinline__ unsigned short f32_to_bf16_rne(float f) {
    unsigned int u = __builtin_bit_cast(unsigned int, f);
    u = (u + 0x7FFFu + ((u >> 16) & 1u)) >> 16;
    return (unsigned short)u;
}

__device__ __forceinline__ float fast_tanh(float x) {
    float cx = fminf(fmaxf(x, -30.f), 30.f);
    float e = __expf(2.f * cx);
    return (e - 1.f) / (e + 1.f);
}

// K0b: pack w_smiles [1024][512] f32 into FRAGMENT-MAJOR bf16 (contiguous 1KB frags).
// Bp[frag=atile*32+gks][lane][e] = w[gks*32 + (lane>>4)*8 + e][atile*16 + (lane&15)]
__global__ void k0b_pack(const float* __restrict__ w, unsigned short* __restrict__ Bp) {
    int bid  = blockIdx.x;        // 1024 = 32 atiles * 32 gks
    int lane = threadIdx.x;       // 64
    int atile = bid >> 5, gks = bid & 31;
    int col = atile * 16 + (lane & 15);
    int k0  = gks * 32 + (lane >> 4) * 8;
    unsigned short us[8];
#pragma unroll
    for (int e = 0; e < 8; ++e)
        us[e] = f32_to_bf16_rne(w[(size_t)(k0 + e) * 512 + col]);
    *(uint4*)(Bp + (size_t)bid * 512 + lane * 8) = *(const uint4*)us;
}

// K1a: gc[b][g] = dot(genes[b][g][0..3], w_ngf)
__global__ void k1a_gc(const float4* __restrict__ genes, const float* __restrict__ wngf,
                       float* __restrict__ gc) {
    int i = blockIdx.x * 256 + threadIdx.x;   // 65536 = 32*2048
    float4 g = genes[i];
    gc[i] = g.x * wngf[0] + g.y * wngf[1] + g.z * wngf[2] + g.w * wngf[3];
}

// K1b: x[b][a] += sum_{g in chunk} gc[b][g] * w_genes[g][a]   (x pre-zeroed)
__global__ void k1b_x(const float* __restrict__ gc, const float* __restrict__ wg,
                      float* __restrict__ x) {
    __shared__ float gcl[256];
    int bx = blockIdx.x;              // 512 = 32 b * 2 a-halves * 8 g-chunks
    int b = bx >> 4, ah = (bx >> 3) & 1, gch = bx & 7;
    int g0 = gch * 256;
    gcl[threadIdx.x] = gc[b * 2048 + g0 + threadIdx.x];
    __syncthreads();
    int a = ah * 256 + threadIdx.x;
    float s = 0.f;
#pragma unroll 8
    for (int g = 0; g < 256; ++g) s += gcl[g] * wg[(size_t)(g0 + g) * 512 + a];
    atomicAdd(&x[b * 512 + a], s);
}

// K2: fused GEMM + tanh + dot(v) -> scores.
// Pipelined: BK=128 double-buffered LDS (2x16KB). Per K-tile:
//   issue next tile's global loads -> compute current (4 ks x 16 MFMA)
//   -> convert+ds_write next buffer -> ONE barrier. (T3/T14 structure)
__global__ __launch_bounds__(512, 4) void k2_scores(
    const float* __restrict__ smiles,
    const unsigned short* __restrict__ Bp,
    const float* __restrict__ xraw,
    const float* __restrict__ b_genes,
    const float* __restrict__ b_smiles,
    const float* __restrict__ v,
    float* __restrict__ scores)
{
    __shared__ unsigned short A_lds[2 * 64 * 128];   // 32 KB, XOR-swizzled 256B rows
    const int tid  = threadIdx.x;
    const int wave = tid >> 6;
    const int lane = tid & 63;
    const int l15  = lane & 15;
    const int l4   = lane >> 4;
    const int gm0  = blockIdx.x * 64;            // 1024 blocks
    const int bidx = gm0 >> 11;
    const int wbase = wave * 64;

    // wave's packed-B base: fragments (wave*4+nt)*32 + gks, each 1KB
    const unsigned short* bpp = Bp + (size_t)(wave * 128) * 512 + lane * 8;

    // staging geometry: thread owns 16 consecutive floats of the 64x128 tile
    const int srow = tid >> 3;                   // 0..63
    const int scol = (tid & 7) * 16;             // 0,16,...,112
    const float* sptr = smiles + (size_t)(gm0 + srow) * 1024 + scol;
    const int sswz = (srow & 7) << 4;
    char* wr0 = (char*)A_lds + srow * 256 + (((tid & 7) * 32) ^ sswz);
    char* wr1 = (char*)A_lds + srow * 256 + ((((tid & 7) * 32) + 16) ^ sswz);

    float4 st0, st1, st2, st3;

    const f32x4 zero4 = {0.f, 0.f, 0.f, 0.f};
    f32x4 acc[4][4];
#pragma unroll
    for (int mt = 0; mt < 4; ++mt)
#pragma unroll
        for (int nt = 0; nt < 4; ++nt)
            acc[mt][nt] = zero4;

#define LOADREGS(kt)                                   \
    {   const float* p = sptr + (kt) * 128;            \
        st0 = *(const float4*)(p);                     \
        st1 = *(const float4*)(p + 4);                 \
        st2 = *(const float4*)(p + 8);                 \
        st3 = *(const float4*)(p + 12); }

#define CONVWRITE(buf)                                                     \
    {   union { unsigned short us[8]; uint4 u4; } pa, pb;                  \
        pa.us[0] = f32_to_bf16_rne(st0.x); pa.us[1] = f32_to_bf16_rne(st0.y); \
        pa.us[2] = f32_to_bf16_rne(st0.z); pa.us[3] = f32_to_bf16_rne(st0.w); \
        pa.us[4] = f32_to_bf16_rne(st1.x); pa.us[5] = f32_to_bf16_rne(st1.y); \
        pa.us[6] = f32_to_bf16_rne(st1.z); pa.us[7] = f32_to_bf16_rne(st1.w); \
        pb.us[0] = f32_to_bf16_rne(st2.x); pb.us[1] = f32_to_bf16_rne(st2.y); \
        pb.us[2] = f32_to_bf16_rne(st2.z); pb.us[3] = f32_to_bf16_rne(st2.w); \
        pb.us[4] = f32_to_bf16_rne(st3.x); pb.us[5] = f32_to_bf16_rne(st3.y); \
        pb.us[6] = f32_to_bf16_rne(st3.z); pb.us[7] = f32_to_bf16_rne(st3.w); \
        *(uint4*)(wr0 + (buf) * 16384) = pa.u4;                            \
        *(uint4*)(wr1 + (buf) * 16384) = pb.u4; }

#define COMPUTE(cur, kt)                                                      \
    _Pragma("unroll")                                                         \
    for (int ks4 = 0; ks4 < 4; ++ks4) {                                       \
        int gks = (kt) * 4 + ks4;                                             \
        bf16x8 af[4], bfb[4];                                                 \
        _Pragma("unroll")                                                     \
        for (int nt = 0; nt < 4; ++nt)                                        \
            bfb[nt] = *(const bf16x8*)(bpp + (nt * 32 + gks) * 512);          \
        _Pragma("unroll")                                                     \
        for (int mt = 0; mt < 4; ++mt) {                                      \
            int row = mt * 16 + l15;                                          \
            int byteoff = (cur) * 16384 + row * 256 +                         \
                          ((ks4 * 64 + l4 * 16) ^ ((row & 7) << 4));          \
            af[mt] = *(const bf16x8*)((const char*)A_lds + byteoff);          \
        }                                                                     \
        __builtin_amdgcn_s_setprio(1);                                        \
        _Pragma("unroll")                                                     \
        for (int mt = 0; mt < 4; ++mt)                                        \
            _Pragma("unroll")                                                 \
            for (int nt = 0; nt < 4; ++nt)                                    \
                acc[mt][nt] = __builtin_amdgcn_mfma_f32_16x16x32_bf16(        \
                    af[mt], bfb[nt], acc[mt][nt], 0, 0, 0);                   \
        __builtin_amdgcn_s_setprio(0);                                        \
    }

    // prologue: tile 0 into buf 0
    LOADREGS(0);
    CONVWRITE(0);
    __syncthreads();

    int cur = 0;
#pragma unroll 1
    for (int kt = 0; kt < 7; ++kt) {
        LOADREGS(kt + 1);          // issue early (T14)
        COMPUTE(cur, kt);          // MFMA hides the HBM latency
        CONVWRITE(cur ^ 1);        // implicit vmcnt wait lands here
        __syncthreads();           // one barrier per K-tile
        cur ^= 1;
    }
    COMPUTE(cur, 7);               // tail tile, no staging, no barrier

#undef LOADREGS
#undef CONVWRITE
#undef COMPUTE

    // epilogue: score[row] += sum_a tanh(y + x + b_g + b_s) * v[a]
    float xbv[4], vv[4];
#pragma unroll
    for (int nt = 0; nt < 4; ++nt) {
        int a = wbase + nt * 16 + l15;
        xbv[nt] = xraw[bidx * 512 + a] + b_genes[a] + b_smiles[a];
        vv[nt]  = v[a];
    }
    float rs[4][4];
#pragma unroll
    for (int mt = 0; mt < 4; ++mt)
#pragma unroll
        for (int r = 0; r < 4; ++r)
            rs[mt][r] = 0.f;
#pragma unroll
    for (int mt = 0; mt < 4; ++mt)
#pragma unroll
        for (int nt = 0; nt < 4; ++nt)
#pragma unroll
            for (int r = 0; r < 4; ++r)
                rs[mt][r] += vv[nt] * fast_tanh(acc[mt][nt][r] + xbv[nt]);
#pragma unroll
    for (int mt = 0; mt < 4; ++mt)
#pragma unroll
        for (int r = 0; r < 4; ++r) {
            float s = rs[mt][r];
            s += __shfl_xor(s, 1);
            s += __shfl_xor(s, 2);
            s += __shfl_xor(s, 4);
            s += __shfl_xor(s, 8);
            rs[mt][r] = s;
        }
    if (l15 == 0) {
#pragma unroll
        for (int mt = 0; mt < 4; ++mt)
#pragma unroll
            for (int r = 0; r < 4; ++r)
                atomicAdd(&scores[gm0 + mt * 16 + l4 * 4 + r], rs[mt][r]);
    }
}

// K3: softmax over t per batch
__global__ void k3_softmax(const float* __restrict__ scores, float* __restrict__ alphas) {
    __shared__ float redmax[4], redsum[4];
    int b = blockIdx.x, tid = threadIdx.x;   // 256 threads
    int wave = tid >> 6;
    float sv[8];
    float mx = -1e30f;
#pragma unroll
    for (int i = 0; i < 8; ++i) {
        sv[i] = scores[b * 2048 + i * 256 + tid];
        mx = fmaxf(mx, sv[i]);
    }
#pragma unroll
    for (int m = 32; m >= 1; m >>= 1) mx = fmaxf(mx, __shfl_xor(mx, m));
    if ((tid & 63) == 0) redmax[wave] = mx;
    __syncthreads();
    mx = fmaxf(fmaxf(redmax[0], redmax[1]), fmaxf(redmax[2], redmax[3]));
    float sum = 0.f;
#pragma unroll
    for (int i = 0; i < 8; ++i) {
        sv[i] = __expf(sv[i] - mx);
        sum += sv[i];
    }
#pragma unroll
    for (int m = 32; m >= 1; m >>= 1) sum += __shfl_xor(sum, m);
    if ((tid & 63) == 0) redsum[wave] = sum;
    __syncthreads();
    sum = redsum[0] + redsum[1] + redsum[2] + redsum[3];
    float inv = 1.f / sum;
#pragma unroll
    for (int i = 0; i < 8; ++i) alphas[b * 2048 + i * 256 + tid] = sv[i] * inv;
}

// K4: out[b][h] = sum_t alphas[b][t] * smiles[b][t][h]  (t-split x16, atomic f32)
__global__ void k4_out(const float* __restrict__ smiles,
                       const float* __restrict__ alphas,
                       float* __restrict__ out)
{
    int bx = blockIdx.x;              // 512 = 32 b * 16 t-chunks
    int b  = bx >> 4;
    int tc = bx & 15;
    int h  = threadIdx.x * 4;         // 256 threads -> 1024 h
    const float* sb = smiles + ((size_t)b * 2048 + tc * 128) * 1024;
    const float* al = alphas + b * 2048 + tc * 128;
    float4 acc = {0.f, 0.f, 0.f, 0.f};
#pragma unroll 4
    for (int t = 0; t < 128; ++t) {
        float a = al[t];
        float4 sv = *(const float4*)(sb + (size_t)t * 1024 + h);
        acc.x += a * sv.x;
        acc.y += a * sv.y;
        acc.z += a * sv.z;
        acc.w += a * sv.w;
    }
    float* o = out + b * 1024 + h;
    atomicAdd(o + 0, acc.x);
    atomicAdd(o + 1, acc.y);
    atomicAdd(o + 2, acc.z);
    atomicAdd(o + 3, acc.w);
}

extern "C" void kernel_launch(void* const* d_in, const int* in_sizes, int n_in,
                              void* d_out, int out_size, void* d_ws, size_t ws_size,
                              hipStream_t stream) {
    const float* genes    = (const float*)d_in[0];
    const float* smiles   = (const float*)d_in[1];
    const float* w_ngf    = (const float*)d_in[2];
    const float* w_genes  = (const float*)d_in[3];
    const float* b_genes  = (const float*)d_in[4];
    const float* w_smiles = (const float*)d_in[5];
    const float* b_smiles = (const float*)d_in[6];
    const float* v        = (const float*)d_in[7];
    float* out = (float*)d_out;

    char* ws = (char*)d_ws;
    unsigned short* Bp = (unsigned short*)(ws);                        // 1 MB packed B
    float* gc     = (float*)(ws + (1 << 20));                          // 256 KB
    float* x      = (float*)(ws + (1 << 20) + (256 << 10));            // 64 KB
    float* scores = (float*)(ws + (1 << 20) + (320 << 10));            // 256 KB
    float* alphas = (float*)(ws + (1 << 20) + (576 << 10));            // 256 KB

    hipMemsetAsync(out, 0, (size_t)32 * 1024 * sizeof(float), stream);
    hipMemsetAsync(x, 0, (size_t)(64 + 256) * 1024, stream);

    k0b_pack<<<1024, 64, 0, stream>>>(w_smiles, Bp);
    k1a_gc<<<256, 256, 0, stream>>>((const float4*)genes, w_ngf, gc);
    k1b_x<<<512, 256, 0, stream>>>(gc, w_genes, x);
    k2_scores<<<1024, 512, 0, stream>>>(smiles, Bp, x, b_genes, b_smiles, v, scores);
    k3_softmax<<<32, 256, 0, stream>>>(scores, alphas);
    k4_out<<<512, 256, 0, stream>>>(smiles, alphas, out);
}